// Round 7
// baseline (133.476 us; speedup 1.0000x reference)
//
#include <hip/hip_runtime.h>
#include <hip/hip_fp16.h>

// Reverb via FFT overlap-save cross-correlation. R21 = R20 (3 dispatches,
// fused norm via device barrier) with TREE ARRIVALS.
// R20 post-mortem: backoff+separate poll line recovered 13.5us (134.5->121),
// but ~20us remains: 512 atomicMax + 512 fetch_add all hit ONE 128B line
// whose home is a single L2 bank -- cross-XCD same-line RMWs serialize at
// ~20-40ns each => ~20-40us. Fix: two-level arrival tree.
//   - 16 GROUP lines (32 blocks each): atomicMax+fetch_add per block,
//     parallel across 16 lines => serial depth 64 RMW/line.
//   - group leaders (16) combine onto 1 GLOBAL line (16+16 RMWs).
//   - final leader publishes max bits to 16 REPLICATED publish lines;
//     each block polls replica (lb&15) with s_sleep(32) backoff.
//   - self-serve fallback on global counter (hang-safety, R20).
// Co-residency (proven R18/R20): grid=512, 35KB LDS, launch_bounds(256,2).
// Structure (3 dispatches):
//   K1 fwd1_pack     : pack + 256-pt stage (stride 4096), BIN-major store.
//   K2 fused_mid     : fft4096(X)||fft4096(H), P=conj(X)*H/L, fft4096(P),
//                      twiddle, row store. Zeroes the 33 sync lines.
//   K3 inv_norm_write: final 256-pt -> y in regs -> TREE max barrier ->
//                      scale in regs -> write normalized fp32.
// Decision rule: <=102us => barrier cheap, R22 = single persistent kernel;
// >=115us => arrival skew is structural, revert to R17 split and attack K1/K2.

#define L_FFT (1 << 20)
#define GSTRIDE 273
#define PSCALE (1.0f / 1048576.0f)   // 2^-20 = 1/L (fp16 range; cancels in norm)
#define NBLK_INV 512                 // K3 grid size
#define NGRP 16                      // arrival groups (one 128B line each)
#define GRPSZ (NBLK_INV / NGRP)      // 32 blocks per group
#define GLOB_LINE 16                 // global combine line index
#define PUB_LINE 17                  // publish replicas: lines 17..32
#define SYNC_LINES 33                // total 128B lines used

__device__ __forceinline__ float2 h2f(__half2 h) { return __half22float2(h); }
__device__ __forceinline__ __half2 f2h(float2 v) { return __floats2half2_rn(v.x, v.y); }

__device__ __forceinline__ float2 cmul(float2 a, float2 b) {
    return make_float2(a.x * b.x - a.y * b.y, a.x * b.y + a.y * b.x);
}

__device__ __forceinline__ void rad4(float2 a, float2 b, float2 c, float2 d,
                                     float2& o0, float2& o1, float2& o2, float2& o3) {
    float2 apc = make_float2(a.x + c.x, a.y + c.y);
    float2 amc = make_float2(a.x - c.x, a.y - c.y);
    float2 bpd = make_float2(b.x + d.x, b.y + d.y);
    float2 bmd = make_float2(b.x - d.x, b.y - d.y);
    o0 = make_float2(apc.x + bpd.x, apc.y + bpd.y);
    o2 = make_float2(apc.x - bpd.x, apc.y - bpd.y);
    o1 = make_float2(amc.x + bmd.y, amc.y - bmd.x);
    o3 = make_float2(amc.x - bmd.y, amc.y + bmd.x);
}

// 16-pt DFT, natural order in/out (bench-verified R2-R20).
__device__ __forceinline__ void dft16(float2 x[16]) {
    float2 tt[16];
    rad4(x[0], x[4], x[8],  x[12], tt[0],  tt[1],  tt[2],  tt[3]);
    rad4(x[1], x[5], x[9],  x[13], tt[4],  tt[5],  tt[6],  tt[7]);
    rad4(x[2], x[6], x[10], x[14], tt[8],  tt[9],  tt[10], tt[11]);
    rad4(x[3], x[7], x[11], x[15], tt[12], tt[13], tt[14], tt[15]);
    const float C1 = 0.92387953251128675613f, S1 = 0.38268343236508977173f;
    const float C2 = 0.70710678118654752440f;
    const float2 W1 = make_float2( C1, -S1);
    const float2 W2 = make_float2( C2, -C2);
    const float2 W3 = make_float2( S1, -C1);
    const float2 W6 = make_float2(-C2, -C2);
    const float2 W9 = make_float2(-C1,  S1);
    tt[5]  = cmul(tt[5],  W1);
    tt[6]  = cmul(tt[6],  W2);
    tt[7]  = cmul(tt[7],  W3);
    tt[9]  = cmul(tt[9],  W2);
    tt[10] = make_float2(tt[10].y, -tt[10].x);
    tt[11] = cmul(tt[11], W6);
    tt[13] = cmul(tt[13], W3);
    tt[14] = cmul(tt[14], W6);
    tt[15] = cmul(tt[15], W9);
    rad4(tt[0], tt[4], tt[8],  tt[12], x[0], x[4], x[8],  x[12]);
    rad4(tt[1], tt[5], tt[9],  tt[13], x[1], x[5], x[9],  x[13]);
    rad4(tt[2], tt[6], tt[10], tt[14], x[2], x[6], x[10], x[14]);
    rad4(tt[3], tt[7], tt[11], tt[15], x[3], x[7], x[11], x[15]);
}

// 256-pt FFT across a 16-thread group: input x[q] = element (i+16q), output
// x[q] = bin (i+16q). Plain DFT-256, no scale. No trailing sync.
__device__ __forceinline__ void fft256_core(float2 x[16], int i, int gi,
                                            float2* lds) {
    dft16(x);
    float sa, ca;
    __sincosf(-6.28318530717958647692f * (float)i * (1.0f / 256.0f), &sa, &ca);
    float2 w1 = make_float2(ca, sa);
    float2 w = w1;
#pragma unroll
    for (int k1 = 1; k1 < 16; ++k1) {
        x[k1] = cmul(x[k1], w);
        w = cmul(w, w1);
    }
    float2* base = lds + gi * GSTRIDE;
#pragma unroll
    for (int k1 = 0; k1 < 16; ++k1) base[i * 17 + k1] = x[k1];
    __syncthreads();
#pragma unroll
    for (int q1 = 0; q1 < 16; ++q1) x[q1] = base[q1 * 17 + i];
    dft16(x);
}

// 4096-pt FFT across a 256-thread block: input x[w] = element (tid + 256*w),
// output x[r] = bin (tid + 256*r). Distribution-preserving. No trailing sync.
__device__ __forceinline__ void fft4096_block(float2 x[16], int tid, float2* lds) {
    dft16(x);
    float sa, ca;
    __sincosf(-6.28318530717958647692f * (float)tid * (1.0f / 4096.0f), &sa, &ca);
    float2 w1 = make_float2(ca, sa);
    float2 w = w1;
#pragma unroll
    for (int a = 1; a < 16; ++a) { x[a] = cmul(x[a], w); w = cmul(w, w1); }
#pragma unroll
    for (int a = 0; a < 16; ++a) lds[a * GSTRIDE + tid] = x[a];
    __syncthreads();
    int an = tid & 15, i2 = tid >> 4;
#pragma unroll
    for (int q = 0; q < 16; ++q) x[q] = lds[an * GSTRIDE + i2 + 16 * q];
    __syncthreads();
    fft256_core(x, i2, an, lds);
}

// Pair version: x and h share the two redistribution barriers.
__device__ __forceinline__ void fft4096_pair(float2 x[16], float2 h[16], int tid,
                                             float2* LX, float2* LH) {
    dft16(x);
    dft16(h);
    float sa, ca;
    __sincosf(-6.28318530717958647692f * (float)tid * (1.0f / 4096.0f), &sa, &ca);
    float2 w1 = make_float2(ca, sa);
    float2 w = w1;
#pragma unroll
    for (int a = 1; a < 16; ++a) {
        x[a] = cmul(x[a], w);
        h[a] = cmul(h[a], w);
        w = cmul(w, w1);
    }
#pragma unroll
    for (int a = 0; a < 16; ++a) {
        LX[a * GSTRIDE + tid] = x[a];
        LH[a * GSTRIDE + tid] = h[a];
    }
    __syncthreads();
    int an = tid & 15, i2 = tid >> 4;
#pragma unroll
    for (int q = 0; q < 16; ++q) {
        x[q] = LX[an * GSTRIDE + i2 + 16 * q];
        h[q] = LH[an * GSTRIDE + i2 + 16 * q];
    }
    __syncthreads();
    fft256_core(x, i2, an, LX);
    fft256_core(h, i2, an, LH);   // its internal barrier also fences LX reads
}

// ---- K1: pack + forward 256-pt stage (stride 4096), bin-major store ----
// Y1[4096*b0 + g] = S[g;b0] * e^{-2pi i g*b0/L}.  64B-segment scatter.
__global__ void fwd1_pack(const float* __restrict__ audio,
                          const float* __restrict__ ir,
                          __half2* __restrict__ dst, int N, int M, int V) {
    __shared__ float2 lds[16 * GSTRIDE];
    int tid = threadIdx.x;
    int gi = tid & 15, i = tid >> 4;
    int bx = blockIdx.x, slot = blockIdx.y;
    int g = bx * 16 + gi;
    __half2* db = dst + (size_t)slot * L_FFT;

    float2 x[16];
#pragma unroll
    for (int q2 = 0; q2 < 16; ++q2) {
        int idx = g + (i + 16 * q2) * (L_FFT / 256);
        float2 v;
        if (slot == 0) {
            v = make_float2(audio[idx], audio[idx + V]);
        } else if (slot == 1) {
            float a2 = (idx + 2 * V < N) ? audio[idx + 2 * V] : 0.f;
            float a3 = (idx + 3 * V < N) ? audio[idx + 3 * V] : 0.f;
            v = make_float2(a2, a3);
        } else {
            v = make_float2((idx < M) ? ir[idx] : 0.f, 0.f);
        }
        x[q2] = v;
    }
    fft256_core(x, i, gi, lds);
    // store bins b0 = i+16q with twiddle e^{-2pi i g*b0/L}, bin-major
    float sa, ca;
    float base = -6.28318530717958647692f * (float)g * (1.0f / (float)L_FFT);
    __sincosf(base * (float)i, &sa, &ca);
    float2 w = make_float2(ca, sa);
    __sincosf(base * 16.0f, &sa, &ca);
    float2 w16 = make_float2(ca, sa);
#pragma unroll
    for (int q = 0; q < 16; ++q) {
        db[(size_t)4096 * (i + 16 * q) + g] = f2h(cmul(x[q], w));
        w = cmul(w, w16);
    }
}

// ---- K2: FUSED fwd-final-4096 (X and H) + spectral multiply + inv-first-4096
// Block = one b0-row per slot p. All loads/stores fully coalesced (rows).
// Block (0,0) zeroes words {0,1} of all 33 sync lines (strictly before K3;
// device-visible at kernel boundary; re-zeroed each iter vs poison fills).
__global__ __launch_bounds__(256, 2) void fused_mid(const __half2* __restrict__ Y1,
                                                    __half2* __restrict__ Mp,
                                                    unsigned* __restrict__ sync) {
    __shared__ float2 LX[16 * GSTRIDE];
    __shared__ float2 LH[16 * GSTRIDE];
    int tid = threadIdx.x;
    int b0 = blockIdx.x, p = blockIdx.y;
    if (b0 == 0 && p == 0 && tid < SYNC_LINES) {
        sync[tid * 32 + 0] = 0u;
        sync[tid * 32 + 1] = 0u;
    }
    const __half2* xr = Y1 + (size_t)p * L_FFT + (size_t)4096 * b0;
    const __half2* hr = Y1 + (size_t)2 * L_FFT + (size_t)4096 * b0;
    float2 x[16], h[16];
#pragma unroll
    for (int w = 0; w < 16; ++w) {
        x[w] = h2f(xr[tid + 256 * w]);
        h[w] = h2f(hr[tid + 256 * w]);
    }
    fft4096_pair(x, h, tid, LX, LH);
    // P~ = conj(X)*H / L  (conjugated spectrum -> fwd-DFT chain = IFFT; R15)
#pragma unroll
    for (int r = 0; r < 16; ++r) {
        float2 Z = x[r], H = h[r];
        x[r] = make_float2((Z.x * H.x + Z.y * H.y) * PSCALE,
                           (Z.x * H.y - Z.y * H.x) * PSCALE);
    }
    fft4096_block(x, tid, LX);
    // twiddle e^{-2pi i b0*n_a/L}, n_a = tid + 256r; coalesced row store
    float sa, ca;
    float base = -6.28318530717958647692f * (float)b0 * (1.0f / (float)L_FFT);
    __sincosf(base * (float)tid, &sa, &ca);
    float2 w = make_float2(ca, sa);
    __sincosf(base * 256.0f, &sa, &ca);
    float2 ws = make_float2(ca, sa);
    __half2* dst = Mp + (size_t)p * L_FFT + (size_t)4096 * b0;
#pragma unroll
    for (int r = 0; r < 16; ++r) {
        dst[tid + 256 * r] = f2h(cmul(x[r], w));
        w = cmul(w, ws);
    }
}

// ---- K3: inverse final 256-pt + TREE max barrier + normalized write ----
// y~[n_a + 4096 n_b] = sum_b0 M'[b0; n_a] e^{-2pi i b0 n_b/256}.
// n = n_a + 4096*i + 65536*r with n_a = 16bx+gi, bins n_b = i+16r.
__global__ __launch_bounds__(256, 2) void inv_norm_write(
        const __half2* __restrict__ Mp, float* __restrict__ out,
        unsigned* __restrict__ sync, int N, int V) {
    __shared__ float2 lds[16 * GSTRIDE];
    __shared__ float sm[4];
    __shared__ float bcast;
    int tid = threadIdx.x;
    int gi = tid & 15, i = tid >> 4;
    int bx = blockIdx.x, p = blockIdx.y;
    const __half2* sb = Mp + (size_t)p * L_FFT;
    int na = 16 * bx + gi;
    float2 x[16];
#pragma unroll
    for (int q = 0; q < 16; ++q)
        x[q] = h2f(sb[(size_t)4096 * (i + 16 * q) + na]);
    fft256_core(x, i, gi, lds);
    int nbase = na + 4096 * i;
    int lenO = (p == 1) ? (N - 3 * V) : V;
    float m = 0.f;
#pragma unroll
    for (int r = 0; r < 16; ++r) {
        int n = nbase + r * 65536;
        if (n < V)    m = fmaxf(m, fabsf(x[r].x));
        if (n < lenO) m = fmaxf(m, fabsf(x[r].y));
    }
    for (int o = 32; o > 0; o >>= 1) m = fmaxf(m, __shfl_xor(m, o));
    int lane = tid & 63, wv = tid >> 6;
    if (lane == 0) sm[wv] = m;
    __syncthreads();
    if (tid == 0) {
        float bm = fmaxf(fmaxf(sm[0], sm[1]), fmaxf(sm[2], sm[3]));
        int lb = (p << 8) | bx;          // linear block id in [0,512)
        int grp = lb & (NGRP - 1);
        unsigned* gl = sync + grp * 32;          // group line
        unsigned* gg = sync + GLOB_LINE * 32;    // global line
        unsigned* pub = sync + (PUB_LINE + grp) * 32;  // my publish replica
        atomicMax(&gl[0], __float_as_uint(bm));
        unsigned old = __hip_atomic_fetch_add(&gl[1], 1u, __ATOMIC_ACQ_REL,
                                              __HIP_MEMORY_SCOPE_AGENT);
        if (old == GRPSZ - 1) {
            // group leader: combine group max into global line
            unsigned gm = __hip_atomic_load(&gl[0], __ATOMIC_ACQUIRE,
                                            __HIP_MEMORY_SCOPE_AGENT);
            atomicMax(&gg[0], gm);
            unsigned gold = __hip_atomic_fetch_add(&gg[1], 1u, __ATOMIC_ACQ_REL,
                                                   __HIP_MEMORY_SCOPE_AGENT);
            if (gold == NGRP - 1) {
                // final leader: publish to all 16 replicas
                unsigned total = __hip_atomic_load(&gg[0], __ATOMIC_ACQUIRE,
                                                   __HIP_MEMORY_SCOPE_AGENT);
#pragma unroll
                for (int k = 0; k < NGRP; ++k)
                    __hip_atomic_store(sync + (PUB_LINE + k) * 32, total,
                                       __ATOMIC_RELEASE, __HIP_MEMORY_SCOPE_AGENT);
            }
        }
        unsigned v;
        for (;;) {
            v = __hip_atomic_load(pub, __ATOMIC_ACQUIRE,
                                  __HIP_MEMORY_SCOPE_AGENT);
            if (v != 0u) break;
            __builtin_amdgcn_s_sleep(32);   // ~0.85us backoff
            // self-serve fallback (hang-safety): all groups arrived?
            if (__hip_atomic_load(&gg[1], __ATOMIC_ACQUIRE,
                                  __HIP_MEMORY_SCOPE_AGENT) >= NGRP) {
                v = __hip_atomic_load(&gg[0], __ATOMIC_ACQUIRE,
                                      __HIP_MEMORY_SCOPE_AGENT);
                break;
            }
        }
        bcast = __uint_as_float(v);
    }
    __syncthreads();
    float inv = 1.0f / bcast;
    int se = 2 * p, so = 2 * p + 1;
#pragma unroll
    for (int r = 0; r < 16; ++r) {
        int n = nbase + r * 65536;
        if (n < V)    out[(size_t)se * V + n] = x[r].x * inv;
        if (n < lenO) out[(size_t)so * V + n] = -x[r].y * inv;
    }
}

extern "C" void kernel_launch(void* const* d_in, const int* in_sizes, int n_in,
                              void* d_out, int out_size, void* d_ws, size_t ws_size,
                              hipStream_t stream) {
    const float* audio = (const float*)d_in[0];
    const float* ir    = (const float*)d_in[1];
    float* out = (float*)d_out;

    const int N = in_sizes[0];          // 2,646,000
    const int M = in_sizes[1];          // 220,500
    const int V = L_FFT - M + 1;        // 828,077

    __half2* A = (__half2*)d_ws;                       // 3L half2 (M' buffer)
    __half2* B = A + (size_t)3 * L_FFT;                // 3L half2 (Y1 buffer)
    unsigned* sync = (unsigned*)(B + (size_t)3 * L_FFT); // 33 x 128B lines

    fwd1_pack<<<dim3(256, 3), 256, 0, stream>>>(audio, ir, B, N, M, V);
    fused_mid<<<dim3(256, 2), 256, 0, stream>>>(B, A, sync);
    inv_norm_write<<<dim3(256, 2), 256, 0, stream>>>(A, out, sync, N, V);
}

// Round 8
// 101.089 us; speedup vs baseline: 1.3204x; 1.3204x over previous
//
#include <hip/hip_runtime.h>
#include <hip/hip_fp16.h>

// Reverb via FFT overlap-save cross-correlation. R22 = REVERT to R17 (100.3us
// champion). R18-R21 post-mortem law: a device-wide barrier costs +25-35us on
// this workload REGARDLESS of protocol -- naive spin (R18: +34), de-contended
// backoff polling (R20: +21), two-level arrival tree + replicated publish
// (R21: +33). The residual is phase-1 completion SKEW (gather-heavy inverse
// stage, 2 blocks/CU, high per-block latency variance across XCDs): a barrier
// charges the max block time, the split structure charges the mean (blocks
// retire independently; the next dispatch backfills). Do not revisit barriers.
// Structure (4 dispatches, proven):
//   K1 fwd1_pack    : pack + 256-pt stage (stride 4096), BIN-major store
//                     Y1[4096*b0 + g] * e^{-2pi i g*b0/L} (64B segs).
//   K2 fused_mid    : per b0-row: fft4096(X) || fft4096(H), P=conj(X)*H/L,
//                     fft4096(P), twiddle e^{-2pi i b0*n_a/L}, row store.
//   K3 inv_write_max: final 256-pt over b0 + write unnorm y (fp32) + max
//                     partials (y already in registers -- no recompute).
//   K4 scale_out    : reduce 512 partials, out *= 1/max (float4, in-place).
// Session model (R15-R21): per-kernel content ~free vs the ~10us/dispatch
// serial floor; dispatch count is the lever but 4 is the no-barrier minimum
// (global max forces the K3/K4 boundary; spectral multiply forces K2's).

#define L_FFT (1 << 20)
#define GSTRIDE 273
#define PSCALE (1.0f / 1048576.0f)   // 2^-20 = 1/L (fp16 range; cancels in norm)

__device__ __forceinline__ float2 h2f(__half2 h) { return __half22float2(h); }
__device__ __forceinline__ __half2 f2h(float2 v) { return __floats2half2_rn(v.x, v.y); }

__device__ __forceinline__ float2 cmul(float2 a, float2 b) {
    return make_float2(a.x * b.x - a.y * b.y, a.x * b.y + a.y * b.x);
}

__device__ __forceinline__ void rad4(float2 a, float2 b, float2 c, float2 d,
                                     float2& o0, float2& o1, float2& o2, float2& o3) {
    float2 apc = make_float2(a.x + c.x, a.y + c.y);
    float2 amc = make_float2(a.x - c.x, a.y - c.y);
    float2 bpd = make_float2(b.x + d.x, b.y + d.y);
    float2 bmd = make_float2(b.x - d.x, b.y - d.y);
    o0 = make_float2(apc.x + bpd.x, apc.y + bpd.y);
    o2 = make_float2(apc.x - bpd.x, apc.y - bpd.y);
    o1 = make_float2(amc.x + bmd.y, amc.y - bmd.x);
    o3 = make_float2(amc.x - bmd.y, amc.y + bmd.x);
}

// 16-pt DFT, natural order in/out (bench-verified R2-R21).
__device__ __forceinline__ void dft16(float2 x[16]) {
    float2 tt[16];
    rad4(x[0], x[4], x[8],  x[12], tt[0],  tt[1],  tt[2],  tt[3]);
    rad4(x[1], x[5], x[9],  x[13], tt[4],  tt[5],  tt[6],  tt[7]);
    rad4(x[2], x[6], x[10], x[14], tt[8],  tt[9],  tt[10], tt[11]);
    rad4(x[3], x[7], x[11], x[15], tt[12], tt[13], tt[14], tt[15]);
    const float C1 = 0.92387953251128675613f, S1 = 0.38268343236508977173f;
    const float C2 = 0.70710678118654752440f;
    const float2 W1 = make_float2( C1, -S1);
    const float2 W2 = make_float2( C2, -C2);
    const float2 W3 = make_float2( S1, -C1);
    const float2 W6 = make_float2(-C2, -C2);
    const float2 W9 = make_float2(-C1,  S1);
    tt[5]  = cmul(tt[5],  W1);
    tt[6]  = cmul(tt[6],  W2);
    tt[7]  = cmul(tt[7],  W3);
    tt[9]  = cmul(tt[9],  W2);
    tt[10] = make_float2(tt[10].y, -tt[10].x);
    tt[11] = cmul(tt[11], W6);
    tt[13] = cmul(tt[13], W3);
    tt[14] = cmul(tt[14], W6);
    tt[15] = cmul(tt[15], W9);
    rad4(tt[0], tt[4], tt[8],  tt[12], x[0], x[4], x[8],  x[12]);
    rad4(tt[1], tt[5], tt[9],  tt[13], x[1], x[5], x[9],  x[13]);
    rad4(tt[2], tt[6], tt[10], tt[14], x[2], x[6], x[10], x[14]);
    rad4(tt[3], tt[7], tt[11], tt[15], x[3], x[7], x[11], x[15]);
}

// 256-pt FFT across a 16-thread group: input x[q] = element (i+16q), output
// x[q] = bin (i+16q). Plain DFT-256, no scale. No trailing sync.
__device__ __forceinline__ void fft256_core(float2 x[16], int i, int gi,
                                            float2* lds) {
    dft16(x);
    float sa, ca;
    __sincosf(-6.28318530717958647692f * (float)i * (1.0f / 256.0f), &sa, &ca);
    float2 w1 = make_float2(ca, sa);
    float2 w = w1;
#pragma unroll
    for (int k1 = 1; k1 < 16; ++k1) {
        x[k1] = cmul(x[k1], w);
        w = cmul(w, w1);
    }
    float2* base = lds + gi * GSTRIDE;
#pragma unroll
    for (int k1 = 0; k1 < 16; ++k1) base[i * 17 + k1] = x[k1];
    __syncthreads();
#pragma unroll
    for (int q1 = 0; q1 < 16; ++q1) x[q1] = base[q1 * 17 + i];
    dft16(x);
}

// 4096-pt FFT across a 256-thread block: input x[w] = element (tid + 256*w),
// output x[r] = bin (tid + 256*r). Distribution-preserving. No trailing sync.
__device__ __forceinline__ void fft4096_block(float2 x[16], int tid, float2* lds) {
    dft16(x);
    float sa, ca;
    __sincosf(-6.28318530717958647692f * (float)tid * (1.0f / 4096.0f), &sa, &ca);
    float2 w1 = make_float2(ca, sa);
    float2 w = w1;
#pragma unroll
    for (int a = 1; a < 16; ++a) { x[a] = cmul(x[a], w); w = cmul(w, w1); }
#pragma unroll
    for (int a = 0; a < 16; ++a) lds[a * GSTRIDE + tid] = x[a];
    __syncthreads();
    int an = tid & 15, i2 = tid >> 4;
#pragma unroll
    for (int q = 0; q < 16; ++q) x[q] = lds[an * GSTRIDE + i2 + 16 * q];
    __syncthreads();
    fft256_core(x, i2, an, lds);
}

// Pair version: x and h share the two redistribution barriers.
__device__ __forceinline__ void fft4096_pair(float2 x[16], float2 h[16], int tid,
                                             float2* LX, float2* LH) {
    dft16(x);
    dft16(h);
    float sa, ca;
    __sincosf(-6.28318530717958647692f * (float)tid * (1.0f / 4096.0f), &sa, &ca);
    float2 w1 = make_float2(ca, sa);
    float2 w = w1;
#pragma unroll
    for (int a = 1; a < 16; ++a) {
        x[a] = cmul(x[a], w);
        h[a] = cmul(h[a], w);
        w = cmul(w, w1);
    }
#pragma unroll
    for (int a = 0; a < 16; ++a) {
        LX[a * GSTRIDE + tid] = x[a];
        LH[a * GSTRIDE + tid] = h[a];
    }
    __syncthreads();
    int an = tid & 15, i2 = tid >> 4;
#pragma unroll
    for (int q = 0; q < 16; ++q) {
        x[q] = LX[an * GSTRIDE + i2 + 16 * q];
        h[q] = LH[an * GSTRIDE + i2 + 16 * q];
    }
    __syncthreads();
    fft256_core(x, i2, an, LX);
    fft256_core(h, i2, an, LH);   // its internal barrier also fences LX reads
}

// ---- K1: pack + forward 256-pt stage (stride 4096), bin-major store ----
// Y1[4096*b0 + g] = S[g;b0] * e^{-2pi i g*b0/L}.  64B-segment scatter.
__global__ void fwd1_pack(const float* __restrict__ audio,
                          const float* __restrict__ ir,
                          __half2* __restrict__ dst, int N, int M, int V) {
    __shared__ float2 lds[16 * GSTRIDE];
    int tid = threadIdx.x;
    int gi = tid & 15, i = tid >> 4;
    int bx = blockIdx.x, slot = blockIdx.y;
    int g = bx * 16 + gi;
    __half2* db = dst + (size_t)slot * L_FFT;

    float2 x[16];
#pragma unroll
    for (int q2 = 0; q2 < 16; ++q2) {
        int idx = g + (i + 16 * q2) * (L_FFT / 256);
        float2 v;
        if (slot == 0) {
            v = make_float2(audio[idx], audio[idx + V]);
        } else if (slot == 1) {
            float a2 = (idx + 2 * V < N) ? audio[idx + 2 * V] : 0.f;
            float a3 = (idx + 3 * V < N) ? audio[idx + 3 * V] : 0.f;
            v = make_float2(a2, a3);
        } else {
            v = make_float2((idx < M) ? ir[idx] : 0.f, 0.f);
        }
        x[q2] = v;
    }
    fft256_core(x, i, gi, lds);
    // store bins b0 = i+16q with twiddle e^{-2pi i g*b0/L}, bin-major
    float sa, ca;
    float base = -6.28318530717958647692f * (float)g * (1.0f / (float)L_FFT);
    __sincosf(base * (float)i, &sa, &ca);
    float2 w = make_float2(ca, sa);
    __sincosf(base * 16.0f, &sa, &ca);
    float2 w16 = make_float2(ca, sa);
#pragma unroll
    for (int q = 0; q < 16; ++q) {
        db[(size_t)4096 * (i + 16 * q) + g] = f2h(cmul(x[q], w));
        w = cmul(w, w16);
    }
}

// ---- K2: FUSED fwd-final-4096 (X and H) + spectral multiply + inv-first-4096
// Block = one b0-row per slot p. All loads/stores fully coalesced (rows).
__global__ __launch_bounds__(256, 2) void fused_mid(const __half2* __restrict__ Y1,
                                                    __half2* __restrict__ Mp) {
    __shared__ float2 LX[16 * GSTRIDE];
    __shared__ float2 LH[16 * GSTRIDE];
    int tid = threadIdx.x;
    int b0 = blockIdx.x, p = blockIdx.y;
    const __half2* xr = Y1 + (size_t)p * L_FFT + (size_t)4096 * b0;
    const __half2* hr = Y1 + (size_t)2 * L_FFT + (size_t)4096 * b0;
    float2 x[16], h[16];
#pragma unroll
    for (int w = 0; w < 16; ++w) {
        x[w] = h2f(xr[tid + 256 * w]);
        h[w] = h2f(hr[tid + 256 * w]);
    }
    fft4096_pair(x, h, tid, LX, LH);
    // P~ = conj(X)*H / L  (conjugated spectrum -> fwd-DFT chain = IFFT; R15)
#pragma unroll
    for (int r = 0; r < 16; ++r) {
        float2 Z = x[r], H = h[r];
        x[r] = make_float2((Z.x * H.x + Z.y * H.y) * PSCALE,
                           (Z.x * H.y - Z.y * H.x) * PSCALE);
    }
    fft4096_block(x, tid, LX);
    // twiddle e^{-2pi i b0*n_a/L}, n_a = tid + 256r; coalesced row store
    float sa, ca;
    float base = -6.28318530717958647692f * (float)b0 * (1.0f / (float)L_FFT);
    __sincosf(base * (float)tid, &sa, &ca);
    float2 w = make_float2(ca, sa);
    __sincosf(base * 256.0f, &sa, &ca);
    float2 ws = make_float2(ca, sa);
    __half2* dst = Mp + (size_t)p * L_FFT + (size_t)4096 * b0;
#pragma unroll
    for (int r = 0; r < 16; ++r) {
        dst[tid + 256 * r] = f2h(cmul(x[r], w));
        w = cmul(w, ws);
    }
}

// ---- K3: inverse final 256-pt over b0 + write UNNORMALIZED y + max partials
// y~[n_a + 4096 n_b] = sum_b0 M'[b0; n_a] e^{-2pi i b0 n_b/256}.
// n = n_a + 4096*i + 65536*r with n_a = 16bx+gi, bins n_b = i+16r.
__global__ void inv_write_max(const __half2* __restrict__ Mp,
                              float* __restrict__ out,
                              float* __restrict__ partials, int N, int V) {
    __shared__ float2 lds[16 * GSTRIDE];
    int tid = threadIdx.x;
    int gi = tid & 15, i = tid >> 4;
    int bx = blockIdx.x, p = blockIdx.y;
    const __half2* sb = Mp + (size_t)p * L_FFT;
    int na = 16 * bx + gi;
    float2 x[16];
#pragma unroll
    for (int q = 0; q < 16; ++q)
        x[q] = h2f(sb[(size_t)4096 * (i + 16 * q) + na]);
    fft256_core(x, i, gi, lds);
    int nbase = na + 4096 * i;
    int se = 2 * p, so = 2 * p + 1;
    int lenO = (p == 1) ? (N - 3 * V) : V;
    float m = 0.f;
#pragma unroll
    for (int r = 0; r < 16; ++r) {
        int n = nbase + r * 65536;
        if (n < V) {
            out[(size_t)se * V + n] = x[r].x;
            m = fmaxf(m, fabsf(x[r].x));
        }
        if (n < lenO) {
            out[(size_t)so * V + n] = -x[r].y;
            m = fmaxf(m, fabsf(x[r].y));
        }
    }
    for (int o = 32; o > 0; o >>= 1) m = fmaxf(m, __shfl_xor(m, o));
    __shared__ float sm[4];
    int lane = tid & 63, wv = tid >> 6;
    if (lane == 0) sm[wv] = m;
    __syncthreads();
    if (tid == 0)
        partials[blockIdx.y * gridDim.x + blockIdx.x] =
            fmaxf(fmaxf(sm[0], sm[1]), fmaxf(sm[2], sm[3]));
}

// ---- K4: streaming in-place scale: out *= 1/max(partials). ----
// float4 loads issued BEFORE the partials reduction (latency hides under it).
// No LDS FFT, high occupancy: duration = L3-resident 42MB RMW + launch floor.
__global__ void scale_out(float* __restrict__ out,
                          const float* __restrict__ partials, int N) {
    __shared__ float sm[4];
    int tid = threadIdx.x;
    size_t base = ((size_t)blockIdx.x * 256 + tid) * 4;
    bool full = (base + 4 <= (size_t)N);
    float4 v = make_float4(0.f, 0.f, 0.f, 0.f);
    if (full) v = *reinterpret_cast<const float4*>(out + base);

    float m = fmaxf(partials[tid], partials[tid + 256]);
    for (int o = 32; o > 0; o >>= 1) m = fmaxf(m, __shfl_xor(m, o));
    int lane = tid & 63, wv = tid >> 6;
    if (lane == 0) sm[wv] = m;
    __syncthreads();
    float inv = 1.0f / fmaxf(fmaxf(sm[0], sm[1]), fmaxf(sm[2], sm[3]));

    if (full) {
        v.x *= inv; v.y *= inv; v.z *= inv; v.w *= inv;
        *reinterpret_cast<float4*>(out + base) = v;
    } else {
        for (size_t j = base; j < (size_t)N; ++j) out[j] *= inv;
    }
}

extern "C" void kernel_launch(void* const* d_in, const int* in_sizes, int n_in,
                              void* d_out, int out_size, void* d_ws, size_t ws_size,
                              hipStream_t stream) {
    const float* audio = (const float*)d_in[0];
    const float* ir    = (const float*)d_in[1];
    float* out = (float*)d_out;

    const int N = in_sizes[0];          // 2,646,000
    const int M = in_sizes[1];          // 220,500
    const int V = L_FFT - M + 1;        // 828,077

    __half2* A = (__half2*)d_ws;                       // 3L half2 (M' buffer)
    __half2* B = A + (size_t)3 * L_FFT;                // 3L half2 (Y1 buffer)
    float* partials = (float*)(B + (size_t)3 * L_FFT); // 512 floats

    fwd1_pack<<<dim3(256, 3), 256, 0, stream>>>(audio, ir, B, N, M, V);
    fused_mid<<<dim3(256, 2), 256, 0, stream>>>(B, A);
    inv_write_max<<<dim3(256, 2), 256, 0, stream>>>(A, out, partials, N, V);
    const int nblk = (N / 4 + 255) / 256;              // 1 float4 per thread
    scale_out<<<dim3(nblk), 256, 0, stream>>>(out, partials, N);
}